// Round 9
// baseline (200.689 us; speedup 1.0000x reference)
//
#include <hip/hip_runtime.h>
#include <stdint.h>

#define Bv 4
#define Nv 2048
#define Kv 30
#define DIMv 128
#define NROW (Bv * Nv)
#define NEDGE (Bv * Nv * Kv)

// ---------------- Kernel A: O frame precompute -> ws ----------------
__global__ __launch_bounds__(256) void o_kernel(const float* __restrict__ X,
                                                float* __restrict__ O9) {
    int id = blockIdx.x * 256 + threadIdx.x;
    if (id >= NROW) return;
    int b = id >> 11;
    int n = id & (Nv - 1);
    float o[9] = {0.f, 0.f, 0.f, 0.f, 0.f, 0.f, 0.f, 0.f, 0.f};
    if (n >= 1 && n <= Nv - 3) {
        const float* Xb = X + (size_t)b * Nv * 3;
        float lx = Xb[(Nv - 1) * 3 + 0], ly = Xb[(Nv - 1) * 3 + 1], lz = Xb[(Nv - 1) * 3 + 2];
        float ax = Xb[n * 3 + 0] - lx, ay = Xb[n * 3 + 1] - ly, az = Xb[n * 3 + 2] - lz;
        float bx = Xb[(n + 1) * 3 + 0] - lx, by = Xb[(n + 1) * 3 + 1] - ly, bz = Xb[(n + 1) * 3 + 2] - lz;
        float an = fmaxf(sqrtf(ax * ax + ay * ay + az * az), 1e-12f);
        ax /= an; ay /= an; az /= an;
        float bn = fmaxf(sqrtf(bx * bx + by * by + bz * bz), 1e-12f);
        bx /= bn; by /= bn; bz /= bn;
        float cx = ay * bz - az * by, cy = az * bx - ax * bz, cz = ax * by - ay * bx;
        float cn = fmaxf(sqrtf(cx * cx + cy * cy + cz * cz), 1e-12f);
        cx /= cn; cy /= cn; cz /= cn;
        float ox = ax - bx, oy = ay - by, oz = az - bz;
        float on = fmaxf(sqrtf(ox * ox + oy * oy + oz * oz), 1e-12f);
        ox /= on; oy /= on; oz /= on;
        float tx = oy * cz - oz * cy, ty = oz * cx - ox * cz, tz = ox * cy - oy * cx;
        o[0] = ox; o[1] = cx; o[2] = tx;
        o[3] = oy; o[4] = cy; o[5] = ty;
        o[6] = oz; o[7] = cz; o[8] = tz;
    }
#pragma unroll
    for (int i = 0; i < 9; ++i) O9[(size_t)id * 9 + i] = o[i];
}

// ---------------- Kernel B: top-K, 2 rows per wave (ILP), bit-exact ----------------
__global__ __launch_bounds__(256) void topk_kernel(const float* __restrict__ X,
                                                   const float* __restrict__ mask,
                                                   int* __restrict__ idx_ws,
                                                   float* __restrict__ dn_ws,
                                                   float* __restrict__ idxf_out) {
    const int lane = threadIdx.x & 63;
    const int wv = threadIdx.x >> 6;
    const int row0 = blockIdx.x * 8 + wv * 2;
    const int b = row0 >> 11;
    const int n0 = row0 & (Nv - 1);
    const int n1 = n0 + 1;
    const float* Xb = X + (size_t)b * Nv * 3;
    const float* Mb = mask + (size_t)b * Nv;
    const float x0 = Xb[n0 * 3 + 0], y0 = Xb[n0 * 3 + 1], z0 = Xb[n0 * 3 + 2];
    const float x1 = Xb[n1 * 3 + 0], y1 = Xb[n1 * 3 + 1], z1 = Xb[n1 * 3 + 2];
    const float mi0 = Mb[n0], mi1 = Mb[n1];

    uint32_t a0[4][8], a1[4][8];
    uint32_t bmax0 = 0, bmax1 = 0;
#pragma unroll
    for (int gg = 0; gg < 4; ++gg)
#pragma unroll
        for (int s = 0; s < 8; ++s) {
            int j = (gg * 8 + s) * 64 + lane;
            float xj = Xb[j * 3 + 0], yj = Xb[j * 3 + 1], zj = Xb[j * 3 + 2];
            float mj = Mb[j];
            float dx = __fsub_rn(x0, xj), dy = __fsub_rn(y0, yj), dz = __fsub_rn(z0, zj);
            float ss = __fadd_rn(__fadd_rn(__fmul_rn(dx, dx), __fmul_rn(dy, dy)),
                                 __fmul_rn(dz, dz));
            float D = __fmul_rn(__fmul_rn(mi0, mj), __fsqrt_rn(__fadd_rn(ss, 1e-6f)));
            uint32_t bits = __float_as_uint(D);
            a0[gg][s] = bits;
            bmax0 = (bits > bmax0) ? bits : bmax0;
            dx = __fsub_rn(x1, xj); dy = __fsub_rn(y1, yj); dz = __fsub_rn(z1, zj);
            ss = __fadd_rn(__fadd_rn(__fmul_rn(dx, dx), __fmul_rn(dy, dy)),
                           __fmul_rn(dz, dz));
            D = __fmul_rn(__fmul_rn(mi1, mj), __fsqrt_rn(__fadd_rn(ss, 1e-6f)));
            bits = __float_as_uint(D);
            a1[gg][s] = bits;
            bmax1 = (bits > bmax1) ? bits : bmax1;
        }
#pragma unroll
    for (int m = 1; m < 64; m <<= 1) {
        uint32_t o0 = __shfl_xor(bmax0, m, 64);
        uint32_t o1 = __shfl_xor(bmax1, m, 64);
        bmax0 = (o0 > bmax0) ? o0 : bmax0;
        bmax1 = (o1 > bmax1) ? o1 : bmax1;
    }
    const float dmax0 = __uint_as_float(bmax0);
    const float dmax1 = __uint_as_float(bmax1);

    unsigned long long g0[4], g1[4];
#pragma unroll
    for (int gg = 0; gg < 4; ++gg) {
        unsigned long long k0 = ~0ull, k1 = ~0ull;
#pragma unroll
        for (int s = 0; s < 8; ++s) {
            int j = (gg * 8 + s) * 64 + lane;
            float mj = Mb[j];
            float adj0 = __fadd_rn(__uint_as_float(a0[gg][s]),
                                   __fmul_rn(__fsub_rn(1.f, __fmul_rn(mi0, mj)), dmax0));
            float adj1 = __fadd_rn(__uint_as_float(a1[gg][s]),
                                   __fmul_rn(__fsub_rn(1.f, __fmul_rn(mi1, mj)), dmax1));
            uint32_t b0 = __float_as_uint(adj0);
            uint32_t b1 = __float_as_uint(adj1);
            a0[gg][s] = b0;
            a1[gg][s] = b1;
            unsigned long long kk0 = ((unsigned long long)b0 << 32) | (unsigned)j;
            unsigned long long kk1 = ((unsigned long long)b1 << 32) | (unsigned)j;
            k0 = (kk0 < k0) ? kk0 : k0;
            k1 = (kk1 < k1) ? kk1 : k1;
        }
        g0[gg] = k0;
        g1[gg] = k1;
    }

    const int rk0 = row0 * Kv, rk1 = rk0 + Kv;
    for (int p = 0; p < Kv; ++p) {
        unsigned long long tA0 = (g0[0] < g0[1]) ? g0[0] : g0[1];
        unsigned long long tA1 = (g0[2] < g0[3]) ? g0[2] : g0[3];
        unsigned long long keyA = (tA0 < tA1) ? tA0 : tA1;
        unsigned long long tB0 = (g1[0] < g1[1]) ? g1[0] : g1[1];
        unsigned long long tB1 = (g1[2] < g1[3]) ? g1[2] : g1[3];
        unsigned long long keyB = (tB0 < tB1) ? tB0 : tB1;
#pragma unroll
        for (int m = 1; m < 64; m <<= 1) {
            unsigned long long oA = __shfl_xor(keyA, m, 64);
            unsigned long long oB = __shfl_xor(keyB, m, 64);
            keyA = (oA < keyA) ? oA : keyA;
            keyB = (oB < keyB) ? oB : keyB;
        }
        const uint32_t mjA = (uint32_t)(keyA & 0xFFFFFFFFull);
        const uint32_t mjB = (uint32_t)(keyB & 0xFFFFFFFFull);

        if (lane == 0) {
            idx_ws[rk0 + p] = (int)mjA;
            dn_ws[rk0 + p] = __uint_as_float((uint32_t)(keyA >> 32));
            idxf_out[rk0 + p] = (float)mjA;
            idx_ws[rk1 + p] = (int)mjB;
            dn_ws[rk1 + p] = __uint_as_float((uint32_t)(keyB >> 32));
            idxf_out[rk1 + p] = (float)mjB;
        }

#define RESCAN(ARR, GK, G, OS)                                                 \
        {                                                                      \
            unsigned long long kmin = ~0ull;                                   \
            _Pragma("unroll")                                                  \
            for (int s = 0; s < 8; ++s) {                                      \
                uint32_t val = ((uint32_t)s == (OS)) ? 0xFFFFFFFFu : ARR[G][s];\
                ARR[G][s] = val;                                               \
                unsigned long long kk = ((unsigned long long)val << 32) |      \
                    (unsigned)((((G) * 8 + s) << 6) | lane);                   \
                kmin = (kk < kmin) ? kk : kmin;                                \
            }                                                                  \
            GK[G] = kmin;                                                      \
        }
        if ((mjA & 63u) == (uint32_t)lane) {
            const uint32_t ww = mjA >> 6;
            const uint32_t og = ww >> 3;
            const uint32_t os = ww & 7u;
            if (og == 0) RESCAN(a0, g0, 0, os)
            else if (og == 1) RESCAN(a0, g0, 1, os)
            else if (og == 2) RESCAN(a0, g0, 2, os)
            else RESCAN(a0, g0, 3, os)
        }
        if ((mjB & 63u) == (uint32_t)lane) {
            const uint32_t ww = mjB >> 6;
            const uint32_t og = ww >> 3;
            const uint32_t os = ww & 7u;
            if (og == 0) RESCAN(a1, g1, 0, os)
            else if (og == 1) RESCAN(a1, g1, 1, os)
            else if (og == 2) RESCAN(a1, g1, 2, os)
            else RESCAN(a1, g1, 3, os)
        }
#undef RESCAN
    }
}

__device__ __forceinline__ float sgnf(float x) {
    return (x > 0.f) ? 1.f : ((x < 0.f) ? -1.f : 0.f);
}

// ---------------- Kernel F: 40 features per edge; 2 independent edges/thread ----------------
__global__ __launch_bounds__(256) void feat_kernel(const float* __restrict__ X,
                                                   const float* __restrict__ O9,
                                                   const int* __restrict__ idx_ws,
                                                   const float* __restrict__ dn_ws,
                                                   float* __restrict__ feat) {
    const int e0 = blockIdx.x * 256 + threadIdx.x;   // NEDGE/2 exact grid
    int eArr[2] = {e0, e0 + NEDGE / 2};

#pragma unroll
    for (int k = 0; k < 2; ++k) {
        const int e = eArr[k];
        const int row = e / Kv;
        const int n = row & (Nv - 1);
        const int b = row >> 11;
        const int bN = b * Nv;
        const int j = idx_ws[e];
        const float dn = dn_ws[e];

        float f[40];
        const float FREQ[8] = {1.0f, 0.31622776601683794f, 0.1f, 0.031622776601683791f,
                               0.01f, 0.0031622776601683794f, 0.001f, 3.1622776601683794e-4f};
        const float d = (float)(j - n);
#pragma unroll
        for (int p = 0; p < 8; ++p) {
            float ang = d * FREQ[p];
            float s, c;
            sincosf(ang, &s, &c);
            f[p] = c;
            f[8 + p] = s;
        }
#pragma unroll
        for (int r = 0; r < 16; ++r) {
            float mu = (float)r * (20.0f / 15.0f);
            float z = (dn - mu) * 0.8f;
            f[16 + r] = expf(-z * z);
        }
        float oi[9], oj[9];
#pragma unroll
        for (int i = 0; i < 9; ++i) {
            oi[i] = O9[(size_t)row * 9 + i];
            oj[i] = O9[((size_t)bN + j) * 9 + i];
        }
        float dx = X[((size_t)bN + j) * 3 + 0] - X[(size_t)row * 3 + 0];
        float dy = X[((size_t)bN + j) * 3 + 1] - X[(size_t)row * 3 + 1];
        float dz = X[((size_t)bN + j) * 3 + 2] - X[(size_t)row * 3 + 2];
        float u0 = oi[0] * dx + oi[1] * dy + oi[2] * dz;
        float u1 = oi[3] * dx + oi[4] * dy + oi[5] * dz;
        float u2 = oi[6] * dx + oi[7] * dy + oi[8] * dz;
        float un = fmaxf(sqrtf(u0 * u0 + u1 * u1 + u2 * u2), 1e-12f);
        f[32] = u0 / un; f[33] = u1 / un; f[34] = u2 / un;

        float R00 = oi[0] * oj[0] + oi[3] * oj[3] + oi[6] * oj[6];
        float R11 = oi[1] * oj[1] + oi[4] * oj[4] + oi[7] * oj[7];
        float R22 = oi[2] * oj[2] + oi[5] * oj[5] + oi[8] * oj[8];
        float R21 = oi[2] * oj[1] + oi[5] * oj[4] + oi[8] * oj[7];
        float R12 = oi[1] * oj[2] + oi[4] * oj[5] + oi[7] * oj[8];
        float R02 = oi[0] * oj[2] + oi[3] * oj[5] + oi[6] * oj[8];
        float R20 = oi[2] * oj[0] + oi[5] * oj[3] + oi[8] * oj[6];
        float R10 = oi[1] * oj[0] + oi[4] * oj[3] + oi[7] * oj[6];
        float R01 = oi[0] * oj[1] + oi[3] * oj[4] + oi[6] * oj[7];
        float m0 = 0.5f * sqrtf(fabsf(1.0f + (R00 - R11 - R22)));
        float m1 = 0.5f * sqrtf(fabsf(1.0f + (-R00 + R11 - R22)));
        float m2 = 0.5f * sqrtf(fabsf(1.0f + (-R00 - R11 + R22)));
        float s0 = sgnf(R21 - R12);
        float s1 = sgnf(R02 - R20);
        float s2 = sgnf(R10 - R01);
        float tr = 1.0f + R00 + R11 + R22;
        float w4 = sqrtf(fmaxf(tr, 0.f)) * 0.5f;
        float q0 = s0 * m0, q1 = s1 * m1, q2 = s2 * m2;
        float qn = fmaxf(sqrtf(q0 * q0 + q1 * q1 + q2 * q2 + w4 * w4), 1e-12f);
        f[35] = q0 / qn; f[36] = q1 / qn; f[37] = q2 / qn; f[38] = w4 / qn;
        f[39] = 0.f;

        float* fe = feat + (size_t)e * 40;
#pragma unroll
        for (int q = 0; q < 10; ++q) {
            float4 v;
            v.x = f[4 * q + 0]; v.y = f[4 * q + 1];
            v.z = f[4 * q + 2]; v.w = f[4 * q + 3];
            *(float4*)(fe + 4 * q) = v;
        }
    }
}

// ---------------- Kernel G5: edge-per-lane; o[128] in VGPR; W via scalar stream ----------------
__global__ __launch_bounds__(256, 2) void gemm_ln5_kernel(const float* __restrict__ W,
                                                          const float* __restrict__ be,
                                                          const float* __restrict__ gain,
                                                          const float* __restrict__ bias,
                                                          const float* __restrict__ feat,
                                                          float* __restrict__ E) {
    const int e = blockIdx.x * 256 + threadIdx.x;   // NEDGE exact
    const float* fp = feat + (size_t)e * 40;

    float o[DIMv];
#pragma unroll
    for (int c = 0; c < DIMv; ++c) o[c] = be[c];    // uniform -> s_load

    // 9 chunks of 4 K-rows (k=0..35), all W/feat addresses static-or-uniform
#pragma unroll 1
    for (int kb = 0; kb < 9; ++kb) {
        const float4 fv = *(const float4*)(fp + kb * 4);
        const float* Wk = W + (size_t)kb * 4 * DIMv;
#pragma unroll
        for (int c = 0; c < DIMv; ++c) {
            float acc = o[c];
            acc = fmaf(fv.x, Wk[c], acc);
            acc = fmaf(fv.y, Wk[DIMv + c], acc);
            acc = fmaf(fv.z, Wk[2 * DIMv + c], acc);
            acc = fmaf(fv.w, Wk[3 * DIMv + c], acc);
            o[c] = acc;
        }
    }
    {   // tail k=36..38 (W has exactly 39 rows; feat[39]=0 pad unused here)
        const float4 fv = *(const float4*)(fp + 36);
        const float* Wk = W + (size_t)36 * DIMv;
#pragma unroll
        for (int c = 0; c < DIMv; ++c) {
            float acc = o[c];
            acc = fmaf(fv.x, Wk[c], acc);
            acc = fmaf(fv.y, Wk[DIMv + c], acc);
            acc = fmaf(fv.z, Wk[2 * DIMv + c], acc);
            o[c] = acc;
        }
    }

    // per-lane LayerNorm over o[0..127] — zero cross-lane ops
    float s = 0.f, q = 0.f;
#pragma unroll
    for (int c = 0; c < DIMv; ++c) {
        s += o[c];
        q = fmaf(o[c], o[c], q);
    }
    const float mu = s * (1.0f / 128.0f);
    const float var = fmaxf((q - s * mu) * (1.0f / 127.0f), 0.f);
    const float inv = 1.0f / (sqrtf(var) + 1e-6f);

    float* ep = E + (size_t)e * DIMv;
#pragma unroll
    for (int qd = 0; qd < DIMv / 4; ++qd) {
        float4 r;
        r.x = gain[4 * qd + 0] * (o[4 * qd + 0] - mu) * inv + bias[4 * qd + 0];
        r.y = gain[4 * qd + 1] * (o[4 * qd + 1] - mu) * inv + bias[4 * qd + 1];
        r.z = gain[4 * qd + 2] * (o[4 * qd + 2] - mu) * inv + bias[4 * qd + 2];
        r.w = gain[4 * qd + 3] * (o[4 * qd + 3] - mu) * inv + bias[4 * qd + 3];
        *(float4*)(ep + 4 * qd) = r;
    }
}

// ---------------- launcher ----------------
extern "C" void kernel_launch(void* const* d_in, const int* in_sizes, int n_in,
                              void* d_out, int out_size, void* d_ws, size_t ws_size,
                              hipStream_t stream) {
    const float* X = (const float*)d_in[0];
    const float* mask = (const float*)d_in[1];
    const float* W_e = (const float*)d_in[2];
    const float* b_e = (const float*)d_in[3];
    const float* gain = (const float*)d_in[4];
    const float* bias = (const float*)d_in[5];

    float* E = (float*)d_out;
    float* idxf = (float*)d_out + (size_t)NEDGE * DIMv;

    char* ws = (char*)d_ws;
    const size_t off_idx = (size_t)NROW * 9 * 4;
    const size_t off_dn = off_idx + (size_t)NEDGE * 4;
    const size_t off_feat = off_dn + (size_t)NEDGE * 4;
    float* O9 = (float*)ws;
    int* idx_ws = (int*)(ws + off_idx);
    float* dn_ws = (float*)(ws + off_dn);
    float* feat = (float*)(ws + off_feat);

    hipLaunchKernelGGL(o_kernel, dim3((NROW + 255) / 256), dim3(256), 0, stream, X, O9);
    hipLaunchKernelGGL(topk_kernel, dim3(NROW / 8), dim3(256), 0, stream,
                       X, mask, idx_ws, dn_ws, idxf);
    hipLaunchKernelGGL(feat_kernel, dim3(NEDGE / 512), dim3(256), 0, stream,
                       X, O9, idx_ws, dn_ws, feat);
    hipLaunchKernelGGL(gemm_ln5_kernel, dim3(NEDGE / 256), dim3(256), 0, stream,
                       W_e, b_e, gain, bias, feat, E);
}

// Round 10
// 191.462 us; speedup vs baseline: 1.0482x; 1.0482x over previous
//
#include <hip/hip_runtime.h>
#include <stdint.h>

#define Bv 4
#define Nv 2048
#define Kv 30
#define DIMv 128
#define NROW (Bv * Nv)
#define NEDGE (Bv * Nv * Kv)

// ---------------- Kernel A: O frame precompute -> ws ----------------
__global__ __launch_bounds__(256) void o_kernel(const float* __restrict__ X,
                                                float* __restrict__ O9) {
    int id = blockIdx.x * 256 + threadIdx.x;
    if (id >= NROW) return;
    int b = id >> 11;
    int n = id & (Nv - 1);
    float o[9] = {0.f, 0.f, 0.f, 0.f, 0.f, 0.f, 0.f, 0.f, 0.f};
    if (n >= 1 && n <= Nv - 3) {
        const float* Xb = X + (size_t)b * Nv * 3;
        float lx = Xb[(Nv - 1) * 3 + 0], ly = Xb[(Nv - 1) * 3 + 1], lz = Xb[(Nv - 1) * 3 + 2];
        float ax = Xb[n * 3 + 0] - lx, ay = Xb[n * 3 + 1] - ly, az = Xb[n * 3 + 2] - lz;
        float bx = Xb[(n + 1) * 3 + 0] - lx, by = Xb[(n + 1) * 3 + 1] - ly, bz = Xb[(n + 1) * 3 + 2] - lz;
        float an = fmaxf(sqrtf(ax * ax + ay * ay + az * az), 1e-12f);
        ax /= an; ay /= an; az /= an;
        float bn = fmaxf(sqrtf(bx * bx + by * by + bz * bz), 1e-12f);
        bx /= bn; by /= bn; bz /= bn;
        float cx = ay * bz - az * by, cy = az * bx - ax * bz, cz = ax * by - ay * bx;
        float cn = fmaxf(sqrtf(cx * cx + cy * cy + cz * cz), 1e-12f);
        cx /= cn; cy /= cn; cz /= cn;
        float ox = ax - bx, oy = ay - by, oz = az - bz;
        float on = fmaxf(sqrtf(ox * ox + oy * oy + oz * oz), 1e-12f);
        ox /= on; oy /= on; oz /= on;
        float tx = oy * cz - oz * cy, ty = oz * cx - ox * cz, tz = ox * cy - oy * cx;
        o[0] = ox; o[1] = cx; o[2] = tx;
        o[3] = oy; o[4] = cy; o[5] = ty;
        o[6] = oz; o[7] = cz; o[8] = tz;
    }
#pragma unroll
    for (int i = 0; i < 9; ++i) O9[(size_t)id * 9 + i] = o[i];
}

// ---------------- Kernel B: top-K, 2 rows per wave (ILP), bit-exact ----------------
__global__ __launch_bounds__(256) void topk_kernel(const float* __restrict__ X,
                                                   const float* __restrict__ mask,
                                                   int* __restrict__ idx_ws,
                                                   float* __restrict__ dn_ws,
                                                   float* __restrict__ idxf_out) {
    const int lane = threadIdx.x & 63;
    const int wv = threadIdx.x >> 6;
    const int row0 = blockIdx.x * 8 + wv * 2;
    const int b = row0 >> 11;
    const int n0 = row0 & (Nv - 1);
    const int n1 = n0 + 1;
    const float* Xb = X + (size_t)b * Nv * 3;
    const float* Mb = mask + (size_t)b * Nv;
    const float x0 = Xb[n0 * 3 + 0], y0 = Xb[n0 * 3 + 1], z0 = Xb[n0 * 3 + 2];
    const float x1 = Xb[n1 * 3 + 0], y1 = Xb[n1 * 3 + 1], z1 = Xb[n1 * 3 + 2];
    const float mi0 = Mb[n0], mi1 = Mb[n1];

    uint32_t a0[4][8], a1[4][8];
    uint32_t bmax0 = 0, bmax1 = 0;
#pragma unroll
    for (int gg = 0; gg < 4; ++gg)
#pragma unroll
        for (int s = 0; s < 8; ++s) {
            int j = (gg * 8 + s) * 64 + lane;
            float xj = Xb[j * 3 + 0], yj = Xb[j * 3 + 1], zj = Xb[j * 3 + 2];
            float mj = Mb[j];
            float dx = __fsub_rn(x0, xj), dy = __fsub_rn(y0, yj), dz = __fsub_rn(z0, zj);
            float ss = __fadd_rn(__fadd_rn(__fmul_rn(dx, dx), __fmul_rn(dy, dy)),
                                 __fmul_rn(dz, dz));
            float D = __fmul_rn(__fmul_rn(mi0, mj), __fsqrt_rn(__fadd_rn(ss, 1e-6f)));
            uint32_t bits = __float_as_uint(D);
            a0[gg][s] = bits;
            bmax0 = (bits > bmax0) ? bits : bmax0;
            dx = __fsub_rn(x1, xj); dy = __fsub_rn(y1, yj); dz = __fsub_rn(z1, zj);
            ss = __fadd_rn(__fadd_rn(__fmul_rn(dx, dx), __fmul_rn(dy, dy)),
                           __fmul_rn(dz, dz));
            D = __fmul_rn(__fmul_rn(mi1, mj), __fsqrt_rn(__fadd_rn(ss, 1e-6f)));
            bits = __float_as_uint(D);
            a1[gg][s] = bits;
            bmax1 = (bits > bmax1) ? bits : bmax1;
        }
#pragma unroll
    for (int m = 1; m < 64; m <<= 1) {
        uint32_t o0 = __shfl_xor(bmax0, m, 64);
        uint32_t o1 = __shfl_xor(bmax1, m, 64);
        bmax0 = (o0 > bmax0) ? o0 : bmax0;
        bmax1 = (o1 > bmax1) ? o1 : bmax1;
    }
    const float dmax0 = __uint_as_float(bmax0);
    const float dmax1 = __uint_as_float(bmax1);

    unsigned long long g0[4], g1[4];
#pragma unroll
    for (int gg = 0; gg < 4; ++gg) {
        unsigned long long k0 = ~0ull, k1 = ~0ull;
#pragma unroll
        for (int s = 0; s < 8; ++s) {
            int j = (gg * 8 + s) * 64 + lane;
            float mj = Mb[j];
            float adj0 = __fadd_rn(__uint_as_float(a0[gg][s]),
                                   __fmul_rn(__fsub_rn(1.f, __fmul_rn(mi0, mj)), dmax0));
            float adj1 = __fadd_rn(__uint_as_float(a1[gg][s]),
                                   __fmul_rn(__fsub_rn(1.f, __fmul_rn(mi1, mj)), dmax1));
            uint32_t b0 = __float_as_uint(adj0);
            uint32_t b1 = __float_as_uint(adj1);
            a0[gg][s] = b0;
            a1[gg][s] = b1;
            unsigned long long kk0 = ((unsigned long long)b0 << 32) | (unsigned)j;
            unsigned long long kk1 = ((unsigned long long)b1 << 32) | (unsigned)j;
            k0 = (kk0 < k0) ? kk0 : k0;
            k1 = (kk1 < k1) ? kk1 : k1;
        }
        g0[gg] = k0;
        g1[gg] = k1;
    }

    const int rk0 = row0 * Kv, rk1 = rk0 + Kv;
    for (int p = 0; p < Kv; ++p) {
        unsigned long long tA0 = (g0[0] < g0[1]) ? g0[0] : g0[1];
        unsigned long long tA1 = (g0[2] < g0[3]) ? g0[2] : g0[3];
        unsigned long long keyA = (tA0 < tA1) ? tA0 : tA1;
        unsigned long long tB0 = (g1[0] < g1[1]) ? g1[0] : g1[1];
        unsigned long long tB1 = (g1[2] < g1[3]) ? g1[2] : g1[3];
        unsigned long long keyB = (tB0 < tB1) ? tB0 : tB1;
#pragma unroll
        for (int m = 1; m < 64; m <<= 1) {
            unsigned long long oA = __shfl_xor(keyA, m, 64);
            unsigned long long oB = __shfl_xor(keyB, m, 64);
            keyA = (oA < keyA) ? oA : keyA;
            keyB = (oB < keyB) ? oB : keyB;
        }
        const uint32_t mjA = (uint32_t)(keyA & 0xFFFFFFFFull);
        const uint32_t mjB = (uint32_t)(keyB & 0xFFFFFFFFull);

        if (lane == 0) {
            idx_ws[rk0 + p] = (int)mjA;
            dn_ws[rk0 + p] = __uint_as_float((uint32_t)(keyA >> 32));
            idxf_out[rk0 + p] = (float)mjA;
            idx_ws[rk1 + p] = (int)mjB;
            dn_ws[rk1 + p] = __uint_as_float((uint32_t)(keyB >> 32));
            idxf_out[rk1 + p] = (float)mjB;
        }

#define RESCAN(ARR, GK, G, OS)                                                 \
        {                                                                      \
            unsigned long long kmin = ~0ull;                                   \
            _Pragma("unroll")                                                  \
            for (int s = 0; s < 8; ++s) {                                      \
                uint32_t val = ((uint32_t)s == (OS)) ? 0xFFFFFFFFu : ARR[G][s];\
                ARR[G][s] = val;                                               \
                unsigned long long kk = ((unsigned long long)val << 32) |      \
                    (unsigned)((((G) * 8 + s) << 6) | lane);                   \
                kmin = (kk < kmin) ? kk : kmin;                                \
            }                                                                  \
            GK[G] = kmin;                                                      \
        }
        if ((mjA & 63u) == (uint32_t)lane) {
            const uint32_t ww = mjA >> 6;
            const uint32_t og = ww >> 3;
            const uint32_t os = ww & 7u;
            if (og == 0) RESCAN(a0, g0, 0, os)
            else if (og == 1) RESCAN(a0, g0, 1, os)
            else if (og == 2) RESCAN(a0, g0, 2, os)
            else RESCAN(a0, g0, 3, os)
        }
        if ((mjB & 63u) == (uint32_t)lane) {
            const uint32_t ww = mjB >> 6;
            const uint32_t og = ww >> 3;
            const uint32_t os = ww & 7u;
            if (og == 0) RESCAN(a1, g1, 0, os)
            else if (og == 1) RESCAN(a1, g1, 1, os)
            else if (og == 2) RESCAN(a1, g1, 2, os)
            else RESCAN(a1, g1, 3, os)
        }
#undef RESCAN
    }
}

__device__ __forceinline__ float sgnf(float x) {
    return (x > 0.f) ? 1.f : ((x < 0.f) ? -1.f : 0.f);
}

// ---------------- Kernel F: 40 features per edge; TRANSPOSED layout [10][NEDGE] ----------------
__global__ __launch_bounds__(256) void feat_kernel(const float* __restrict__ X,
                                                   const float* __restrict__ O9,
                                                   const int* __restrict__ idx_ws,
                                                   const float* __restrict__ dn_ws,
                                                   float4* __restrict__ feat4) {
    const int e = blockIdx.x * 256 + threadIdx.x;   // NEDGE exact
    const int row = e / Kv;
    const int n = row & (Nv - 1);
    const int b = row >> 11;
    const int bN = b * Nv;
    const int j = idx_ws[e];
    const float dn = dn_ws[e];

    float f[40];
    const float FREQ[8] = {1.0f, 0.31622776601683794f, 0.1f, 0.031622776601683791f,
                           0.01f, 0.0031622776601683794f, 0.001f, 3.1622776601683794e-4f};
    const float d = (float)(j - n);
#pragma unroll
    for (int p = 0; p < 8; ++p) {
        float ang = d * FREQ[p];
        float s, c;
        sincosf(ang, &s, &c);
        f[p] = c;
        f[8 + p] = s;
    }
#pragma unroll
    for (int r = 0; r < 16; ++r) {
        float mu = (float)r * (20.0f / 15.0f);
        float z = (dn - mu) * 0.8f;
        f[16 + r] = expf(-z * z);
    }
    float oi[9], oj[9];
#pragma unroll
    for (int i = 0; i < 9; ++i) {
        oi[i] = O9[(size_t)row * 9 + i];
        oj[i] = O9[((size_t)bN + j) * 9 + i];
    }
    float dx = X[((size_t)bN + j) * 3 + 0] - X[(size_t)row * 3 + 0];
    float dy = X[((size_t)bN + j) * 3 + 1] - X[(size_t)row * 3 + 1];
    float dz = X[((size_t)bN + j) * 3 + 2] - X[(size_t)row * 3 + 2];
    float u0 = oi[0] * dx + oi[1] * dy + oi[2] * dz;
    float u1 = oi[3] * dx + oi[4] * dy + oi[5] * dz;
    float u2 = oi[6] * dx + oi[7] * dy + oi[8] * dz;
    float un = fmaxf(sqrtf(u0 * u0 + u1 * u1 + u2 * u2), 1e-12f);
    f[32] = u0 / un; f[33] = u1 / un; f[34] = u2 / un;

    float R00 = oi[0] * oj[0] + oi[3] * oj[3] + oi[6] * oj[6];
    float R11 = oi[1] * oj[1] + oi[4] * oj[4] + oi[7] * oj[7];
    float R22 = oi[2] * oj[2] + oi[5] * oj[5] + oi[8] * oj[8];
    float R21 = oi[2] * oj[1] + oi[5] * oj[4] + oi[8] * oj[7];
    float R12 = oi[1] * oj[2] + oi[4] * oj[5] + oi[7] * oj[8];
    float R02 = oi[0] * oj[2] + oi[3] * oj[5] + oi[6] * oj[8];
    float R20 = oi[2] * oj[0] + oi[5] * oj[3] + oi[8] * oj[6];
    float R10 = oi[1] * oj[0] + oi[4] * oj[3] + oi[7] * oj[6];
    float R01 = oi[0] * oj[1] + oi[3] * oj[4] + oi[6] * oj[7];
    float m0 = 0.5f * sqrtf(fabsf(1.0f + (R00 - R11 - R22)));
    float m1 = 0.5f * sqrtf(fabsf(1.0f + (-R00 + R11 - R22)));
    float m2 = 0.5f * sqrtf(fabsf(1.0f + (-R00 - R11 + R22)));
    float s0 = sgnf(R21 - R12);
    float s1 = sgnf(R02 - R20);
    float s2 = sgnf(R10 - R01);
    float tr = 1.0f + R00 + R11 + R22;
    float w4 = sqrtf(fmaxf(tr, 0.f)) * 0.5f;
    float q0 = s0 * m0, q1 = s1 * m1, q2 = s2 * m2;
    float qn = fmaxf(sqrtf(q0 * q0 + q1 * q1 + q2 * q2 + w4 * w4), 1e-12f);
    f[35] = q0 / qn; f[36] = q1 / qn; f[37] = q2 / qn; f[38] = w4 / qn;
    f[39] = 0.f;

    // transposed, fully coalesced stores: feat4[q][e]
#pragma unroll
    for (int q = 0; q < 10; ++q) {
        float4 v;
        v.x = f[4 * q + 0]; v.y = f[4 * q + 1];
        v.z = f[4 * q + 2]; v.w = f[4 * q + 3];
        feat4[(size_t)q * NEDGE + e] = v;
    }
}

// ---------------- Kernel G6: wave/row, 2ch/lane; scalar W arrays (pin) + feat dbuf ----------------
__global__ __launch_bounds__(256, 2) void gemm_ln6_kernel(const float* __restrict__ W,
                                                          const float* __restrict__ be,
                                                          const float* __restrict__ gain,
                                                          const float* __restrict__ bias,
                                                          const float4* __restrict__ feat4,
                                                          float* __restrict__ E) {
    const int lane = threadIdx.x & 63;
    const int w = threadIdx.x >> 6;
    const int row = blockIdx.x * 4 + w;
    const int rk = row * Kv;
    const int c0 = lane, c1 = lane + 64;

    // W as scalar float arrays — the ONLY pattern the compiler has pinned (R3: VGPR=104)
    float w0[40], w1[40];
#pragma unroll
    for (int i = 0; i < 39; ++i) {
        w0[i] = W[i * DIMv + c0];
        w1[i] = W[i * DIMv + c1];
    }
    w0[39] = 0.f; w1[39] = 0.f;
    const float be0 = be[c0], be1 = be[c1];
    const float g0 = gain[c0], g1 = gain[c1];
    const float bb0 = bias[c0], bb1 = bias[c1];

    // feat double buffer: wave-uniform VMEM float4 loads (vmcnt in-order -> pipelined)
    float4 bA[10], bB[10];
#pragma unroll
    for (int q = 0; q < 10; ++q) bA[q] = feat4[(size_t)q * NEDGE + rk];

#define COMPUTE_STORE(BUF, EIDX)                                               \
    {                                                                          \
        float a0 = be0, a1 = be1;                                              \
        _Pragma("unroll")                                                      \
        for (int q = 0; q < 10; ++q) {                                         \
            float4 v = BUF[q];                                                 \
            a0 = fmaf(v.x, w0[4 * q + 0], a0);                                 \
            a1 = fmaf(v.x, w1[4 * q + 0], a1);                                 \
            a0 = fmaf(v.y, w0[4 * q + 1], a0);                                 \
            a1 = fmaf(v.y, w1[4 * q + 1], a1);                                 \
            a0 = fmaf(v.z, w0[4 * q + 2], a0);                                 \
            a1 = fmaf(v.z, w1[4 * q + 2], a1);                                 \
            a0 = fmaf(v.w, w0[4 * q + 3], a0);                                 \
            a1 = fmaf(v.w, w1[4 * q + 3], a1);                                 \
        }                                                                      \
        float s_ = a0 + a1;                                                    \
        float q_ = fmaf(a0, a0, a1 * a1);                                      \
        _Pragma("unroll")                                                      \
        for (int m = 1; m < 64; m <<= 1) {                                     \
            s_ += __shfl_xor(s_, m, 64);                                       \
            q_ += __shfl_xor(q_, m, 64);                                       \
        }                                                                      \
        float mu = s_ * (1.0f / 128.0f);                                       \
        float var = fmaxf((q_ - s_ * mu) * (1.0f / 127.0f), 0.f);              \
        float inv = 1.0f / (sqrtf(var) + 1e-6f);                               \
        float* out = E + (size_t)(rk + (EIDX)) * DIMv;                         \
        out[c0] = g0 * (a0 - mu) * inv + bb0;                                  \
        out[c1] = g1 * (a1 - mu) * inv + bb1;                                  \
    }

    for (int e = 0; e < Kv; e += 2) {
#pragma unroll
        for (int q = 0; q < 10; ++q) bB[q] = feat4[(size_t)q * NEDGE + rk + e + 1];
        COMPUTE_STORE(bA, e)
        {
            int en = (e + 2 < Kv) ? (e + 2) : (Kv - 1);
#pragma unroll
            for (int q = 0; q < 10; ++q) bA[q] = feat4[(size_t)q * NEDGE + rk + en];
        }
        COMPUTE_STORE(bB, e + 1)
    }
#undef COMPUTE_STORE
}

// ---------------- launcher ----------------
extern "C" void kernel_launch(void* const* d_in, const int* in_sizes, int n_in,
                              void* d_out, int out_size, void* d_ws, size_t ws_size,
                              hipStream_t stream) {
    const float* X = (const float*)d_in[0];
    const float* mask = (const float*)d_in[1];
    const float* W_e = (const float*)d_in[2];
    const float* b_e = (const float*)d_in[3];
    const float* gain = (const float*)d_in[4];
    const float* bias = (const float*)d_in[5];

    float* E = (float*)d_out;
    float* idxf = (float*)d_out + (size_t)NEDGE * DIMv;

    char* ws = (char*)d_ws;
    const size_t off_idx = (size_t)NROW * 9 * 4;
    const size_t off_dn = off_idx + (size_t)NEDGE * 4;
    const size_t off_feat = off_dn + (size_t)NEDGE * 4;
    float* O9 = (float*)ws;
    int* idx_ws = (int*)(ws + off_idx);
    float* dn_ws = (float*)(ws + off_dn);
    float4* feat4 = (float4*)(ws + off_feat);   // [10][NEDGE] float4

    hipLaunchKernelGGL(o_kernel, dim3((NROW + 255) / 256), dim3(256), 0, stream, X, O9);
    hipLaunchKernelGGL(topk_kernel, dim3(NROW / 8), dim3(256), 0, stream,
                       X, mask, idx_ws, dn_ws, idxf);
    hipLaunchKernelGGL(feat_kernel, dim3(NEDGE / 256), dim3(256), 0, stream,
                       X, O9, idx_ws, dn_ws, feat4);
    hipLaunchKernelGGL(gemm_ln6_kernel, dim3(NROW / 4), dim3(256), 0, stream,
                       W_e, b_e, gain, bias, feat4, E);
}

// Round 11
// 162.221 us; speedup vs baseline: 1.2371x; 1.1803x over previous
//
#include <hip/hip_runtime.h>
#include <stdint.h>

#define Bv 4
#define Nv 2048
#define Kv 30
#define DIMv 128
#define NROW (Bv * Nv)
#define NEDGE (Bv * Nv * Kv)

// ---------------- Kernel A: O frame precompute -> ws ----------------
__global__ __launch_bounds__(256) void o_kernel(const float* __restrict__ X,
                                                float* __restrict__ O9) {
    int id = blockIdx.x * 256 + threadIdx.x;
    if (id >= NROW) return;
    int b = id >> 11;
    int n = id & (Nv - 1);
    float o[9] = {0.f, 0.f, 0.f, 0.f, 0.f, 0.f, 0.f, 0.f, 0.f};
    if (n >= 1 && n <= Nv - 3) {
        const float* Xb = X + (size_t)b * Nv * 3;
        float lx = Xb[(Nv - 1) * 3 + 0], ly = Xb[(Nv - 1) * 3 + 1], lz = Xb[(Nv - 1) * 3 + 2];
        float ax = Xb[n * 3 + 0] - lx, ay = Xb[n * 3 + 1] - ly, az = Xb[n * 3 + 2] - lz;
        float bx = Xb[(n + 1) * 3 + 0] - lx, by = Xb[(n + 1) * 3 + 1] - ly, bz = Xb[(n + 1) * 3 + 2] - lz;
        float an = fmaxf(sqrtf(ax * ax + ay * ay + az * az), 1e-12f);
        ax /= an; ay /= an; az /= an;
        float bn = fmaxf(sqrtf(bx * bx + by * by + bz * bz), 1e-12f);
        bx /= bn; by /= bn; bz /= bn;
        float cx = ay * bz - az * by, cy = az * bx - ax * bz, cz = ax * by - ay * bx;
        float cn = fmaxf(sqrtf(cx * cx + cy * cy + cz * cz), 1e-12f);
        cx /= cn; cy /= cn; cz /= cn;
        float ox = ax - bx, oy = ay - by, oz = az - bz;
        float on = fmaxf(sqrtf(ox * ox + oy * oy + oz * oz), 1e-12f);
        ox /= on; oy /= on; oz /= on;
        float tx = oy * cz - oz * cy, ty = oz * cx - ox * cz, tz = ox * cy - oy * cx;
        o[0] = ox; o[1] = cx; o[2] = tx;
        o[3] = oy; o[4] = cy; o[5] = ty;
        o[6] = oz; o[7] = cz; o[8] = tz;
    }
#pragma unroll
    for (int i = 0; i < 9; ++i) O9[(size_t)id * 9 + i] = o[i];
}

// ---------------- Kernel B: top-K, 2 rows per wave (ILP), bit-exact ----------------
__global__ __launch_bounds__(256) void topk_kernel(const float* __restrict__ X,
                                                   const float* __restrict__ mask,
                                                   int* __restrict__ idx_ws,
                                                   float* __restrict__ dn_ws,
                                                   float* __restrict__ idxf_out) {
    const int lane = threadIdx.x & 63;
    const int wv = threadIdx.x >> 6;
    const int row0 = blockIdx.x * 8 + wv * 2;
    const int b = row0 >> 11;
    const int n0 = row0 & (Nv - 1);
    const int n1 = n0 + 1;
    const float* Xb = X + (size_t)b * Nv * 3;
    const float* Mb = mask + (size_t)b * Nv;
    const float x0 = Xb[n0 * 3 + 0], y0 = Xb[n0 * 3 + 1], z0 = Xb[n0 * 3 + 2];
    const float x1 = Xb[n1 * 3 + 0], y1 = Xb[n1 * 3 + 1], z1 = Xb[n1 * 3 + 2];
    const float mi0 = Mb[n0], mi1 = Mb[n1];

    uint32_t a0[4][8], a1[4][8];
    uint32_t bmax0 = 0, bmax1 = 0;
#pragma unroll
    for (int gg = 0; gg < 4; ++gg)
#pragma unroll
        for (int s = 0; s < 8; ++s) {
            int j = (gg * 8 + s) * 64 + lane;
            float xj = Xb[j * 3 + 0], yj = Xb[j * 3 + 1], zj = Xb[j * 3 + 2];
            float mj = Mb[j];
            float dx = __fsub_rn(x0, xj), dy = __fsub_rn(y0, yj), dz = __fsub_rn(z0, zj);
            float ss = __fadd_rn(__fadd_rn(__fmul_rn(dx, dx), __fmul_rn(dy, dy)),
                                 __fmul_rn(dz, dz));
            float D = __fmul_rn(__fmul_rn(mi0, mj), __fsqrt_rn(__fadd_rn(ss, 1e-6f)));
            uint32_t bits = __float_as_uint(D);
            a0[gg][s] = bits;
            bmax0 = (bits > bmax0) ? bits : bmax0;
            dx = __fsub_rn(x1, xj); dy = __fsub_rn(y1, yj); dz = __fsub_rn(z1, zj);
            ss = __fadd_rn(__fadd_rn(__fmul_rn(dx, dx), __fmul_rn(dy, dy)),
                           __fmul_rn(dz, dz));
            D = __fmul_rn(__fmul_rn(mi1, mj), __fsqrt_rn(__fadd_rn(ss, 1e-6f)));
            bits = __float_as_uint(D);
            a1[gg][s] = bits;
            bmax1 = (bits > bmax1) ? bits : bmax1;
        }
#pragma unroll
    for (int m = 1; m < 64; m <<= 1) {
        uint32_t o0 = __shfl_xor(bmax0, m, 64);
        uint32_t o1 = __shfl_xor(bmax1, m, 64);
        bmax0 = (o0 > bmax0) ? o0 : bmax0;
        bmax1 = (o1 > bmax1) ? o1 : bmax1;
    }
    const float dmax0 = __uint_as_float(bmax0);
    const float dmax1 = __uint_as_float(bmax1);

    unsigned long long g0[4], g1[4];
#pragma unroll
    for (int gg = 0; gg < 4; ++gg) {
        unsigned long long k0 = ~0ull, k1 = ~0ull;
#pragma unroll
        for (int s = 0; s < 8; ++s) {
            int j = (gg * 8 + s) * 64 + lane;
            float mj = Mb[j];
            float adj0 = __fadd_rn(__uint_as_float(a0[gg][s]),
                                   __fmul_rn(__fsub_rn(1.f, __fmul_rn(mi0, mj)), dmax0));
            float adj1 = __fadd_rn(__uint_as_float(a1[gg][s]),
                                   __fmul_rn(__fsub_rn(1.f, __fmul_rn(mi1, mj)), dmax1));
            uint32_t b0 = __float_as_uint(adj0);
            uint32_t b1 = __float_as_uint(adj1);
            a0[gg][s] = b0;
            a1[gg][s] = b1;
            unsigned long long kk0 = ((unsigned long long)b0 << 32) | (unsigned)j;
            unsigned long long kk1 = ((unsigned long long)b1 << 32) | (unsigned)j;
            k0 = (kk0 < k0) ? kk0 : k0;
            k1 = (kk1 < k1) ? kk1 : k1;
        }
        g0[gg] = k0;
        g1[gg] = k1;
    }

    const int rk0 = row0 * Kv, rk1 = rk0 + Kv;
    for (int p = 0; p < Kv; ++p) {
        unsigned long long tA0 = (g0[0] < g0[1]) ? g0[0] : g0[1];
        unsigned long long tA1 = (g0[2] < g0[3]) ? g0[2] : g0[3];
        unsigned long long keyA = (tA0 < tA1) ? tA0 : tA1;
        unsigned long long tB0 = (g1[0] < g1[1]) ? g1[0] : g1[1];
        unsigned long long tB1 = (g1[2] < g1[3]) ? g1[2] : g1[3];
        unsigned long long keyB = (tB0 < tB1) ? tB0 : tB1;
#pragma unroll
        for (int m = 1; m < 64; m <<= 1) {
            unsigned long long oA = __shfl_xor(keyA, m, 64);
            unsigned long long oB = __shfl_xor(keyB, m, 64);
            keyA = (oA < keyA) ? oA : keyA;
            keyB = (oB < keyB) ? oB : keyB;
        }
        const uint32_t mjA = (uint32_t)(keyA & 0xFFFFFFFFull);
        const uint32_t mjB = (uint32_t)(keyB & 0xFFFFFFFFull);

        if (lane == 0) {
            idx_ws[rk0 + p] = (int)mjA;
            dn_ws[rk0 + p] = __uint_as_float((uint32_t)(keyA >> 32));
            idxf_out[rk0 + p] = (float)mjA;
            idx_ws[rk1 + p] = (int)mjB;
            dn_ws[rk1 + p] = __uint_as_float((uint32_t)(keyB >> 32));
            idxf_out[rk1 + p] = (float)mjB;
        }

#define RESCAN(ARR, GK, G, OS)                                                 \
        {                                                                      \
            unsigned long long kmin = ~0ull;                                   \
            _Pragma("unroll")                                                  \
            for (int s = 0; s < 8; ++s) {                                      \
                uint32_t val = ((uint32_t)s == (OS)) ? 0xFFFFFFFFu : ARR[G][s];\
                ARR[G][s] = val;                                               \
                unsigned long long kk = ((unsigned long long)val << 32) |      \
                    (unsigned)((((G) * 8 + s) << 6) | lane);                   \
                kmin = (kk < kmin) ? kk : kmin;                                \
            }                                                                  \
            GK[G] = kmin;                                                      \
        }
        if ((mjA & 63u) == (uint32_t)lane) {
            const uint32_t ww = mjA >> 6;
            const uint32_t og = ww >> 3;
            const uint32_t os = ww & 7u;
            if (og == 0) RESCAN(a0, g0, 0, os)
            else if (og == 1) RESCAN(a0, g0, 1, os)
            else if (og == 2) RESCAN(a0, g0, 2, os)
            else RESCAN(a0, g0, 3, os)
        }
        if ((mjB & 63u) == (uint32_t)lane) {
            const uint32_t ww = mjB >> 6;
            const uint32_t og = ww >> 3;
            const uint32_t os = ww & 7u;
            if (og == 0) RESCAN(a1, g1, 0, os)
            else if (og == 1) RESCAN(a1, g1, 1, os)
            else if (og == 2) RESCAN(a1, g1, 2, os)
            else RESCAN(a1, g1, 3, os)
        }
#undef RESCAN
    }
}

__device__ __forceinline__ float sgnf(float x) {
    return (x > 0.f) ? 1.f : ((x < 0.f) ? -1.f : 0.f);
}

// ---------------- Kernel F: 40 features per edge; row-major [NEDGE][40] ----------------
__global__ __launch_bounds__(256) void feat_kernel(const float* __restrict__ X,
                                                   const float* __restrict__ O9,
                                                   const int* __restrict__ idx_ws,
                                                   const float* __restrict__ dn_ws,
                                                   float* __restrict__ feat) {
    const int e = blockIdx.x * 256 + threadIdx.x;   // NEDGE exact
    const int row = e / Kv;
    const int n = row & (Nv - 1);
    const int b = row >> 11;
    const int bN = b * Nv;
    const int j = idx_ws[e];
    const float dn = dn_ws[e];

    float f[40];
    const float FREQ[8] = {1.0f, 0.31622776601683794f, 0.1f, 0.031622776601683791f,
                           0.01f, 0.0031622776601683794f, 0.001f, 3.1622776601683794e-4f};
    const float d = (float)(j - n);
#pragma unroll
    for (int p = 0; p < 8; ++p) {
        float ang = d * FREQ[p];
        float s, c;
        sincosf(ang, &s, &c);
        f[p] = c;
        f[8 + p] = s;
    }
#pragma unroll
    for (int r = 0; r < 16; ++r) {
        float mu = (float)r * (20.0f / 15.0f);
        float z = (dn - mu) * 0.8f;
        f[16 + r] = expf(-z * z);
    }
    float oi[9], oj[9];
#pragma unroll
    for (int i = 0; i < 9; ++i) {
        oi[i] = O9[(size_t)row * 9 + i];
        oj[i] = O9[((size_t)bN + j) * 9 + i];
    }
    float dx = X[((size_t)bN + j) * 3 + 0] - X[(size_t)row * 3 + 0];
    float dy = X[((size_t)bN + j) * 3 + 1] - X[(size_t)row * 3 + 1];
    float dz = X[((size_t)bN + j) * 3 + 2] - X[(size_t)row * 3 + 2];
    float u0 = oi[0] * dx + oi[1] * dy + oi[2] * dz;
    float u1 = oi[3] * dx + oi[4] * dy + oi[5] * dz;
    float u2 = oi[6] * dx + oi[7] * dy + oi[8] * dz;
    float un = fmaxf(sqrtf(u0 * u0 + u1 * u1 + u2 * u2), 1e-12f);
    f[32] = u0 / un; f[33] = u1 / un; f[34] = u2 / un;

    float R00 = oi[0] * oj[0] + oi[3] * oj[3] + oi[6] * oj[6];
    float R11 = oi[1] * oj[1] + oi[4] * oj[4] + oi[7] * oj[7];
    float R22 = oi[2] * oj[2] + oi[5] * oj[5] + oi[8] * oj[8];
    float R21 = oi[2] * oj[1] + oi[5] * oj[4] + oi[8] * oj[7];
    float R12 = oi[1] * oj[2] + oi[4] * oj[5] + oi[7] * oj[8];
    float R02 = oi[0] * oj[2] + oi[3] * oj[5] + oi[6] * oj[8];
    float R20 = oi[2] * oj[0] + oi[5] * oj[3] + oi[8] * oj[6];
    float R10 = oi[1] * oj[0] + oi[4] * oj[3] + oi[7] * oj[6];
    float R01 = oi[0] * oj[1] + oi[3] * oj[4] + oi[6] * oj[7];
    float m0 = 0.5f * sqrtf(fabsf(1.0f + (R00 - R11 - R22)));
    float m1 = 0.5f * sqrtf(fabsf(1.0f + (-R00 + R11 - R22)));
    float m2 = 0.5f * sqrtf(fabsf(1.0f + (-R00 - R11 + R22)));
    float s0 = sgnf(R21 - R12);
    float s1 = sgnf(R02 - R20);
    float s2 = sgnf(R10 - R01);
    float tr = 1.0f + R00 + R11 + R22;
    float w4 = sqrtf(fmaxf(tr, 0.f)) * 0.5f;
    float q0 = s0 * m0, q1 = s1 * m1, q2 = s2 * m2;
    float qn = fmaxf(sqrtf(q0 * q0 + q1 * q1 + q2 * q2 + w4 * w4), 1e-12f);
    f[35] = q0 / qn; f[36] = q1 / qn; f[37] = q2 / qn; f[38] = w4 / qn;
    f[39] = 0.f;

    float* fe = feat + (size_t)e * 40;
#pragma unroll
    for (int q = 0; q < 10; ++q) {
        float4 v;
        v.x = f[4 * q + 0]; v.y = f[4 * q + 1];
        v.z = f[4 * q + 2]; v.w = f[4 * q + 3];
        *(float4*)(fe + 4 * q) = v;
    }
}

// ---------------- Kernel G7: wave/row; feat staged to LDS; R3-style pinned W ----------------
__global__ __launch_bounds__(256) void gemm_ln7_kernel(const float* __restrict__ W,
                                                       const float* __restrict__ be,
                                                       const float* __restrict__ gain,
                                                       const float* __restrict__ bias,
                                                       const float* __restrict__ feat,
                                                       float* __restrict__ E) {
    __shared__ float fls[4][Kv * 40];   // 4.8 KB per wave, 19.2 KB per block

    const int lane = threadIdx.x & 63;
    const int w = threadIdx.x >> 6;
    const int row = blockIdx.x * 4 + w;
    const int rk = row * Kv;
    const int c0 = lane, c1 = lane + 64;

    // stage the whole row's features: 300 float4, perfectly coalesced, ONE wait
    {
        const float* fb = feat + (size_t)rk * 40;
#pragma unroll
        for (int r = 0; r < 5; ++r) {
            int idx = r * 64 + lane;
            if (idx < 300) {
                float4 v = *(const float4*)(fb + idx * 4);
                *(float4*)(&fls[w][idx * 4]) = v;
            }
        }
    }

    // W in scalar arrays — the loop body below matches R3's proven pin shape
    float w0[40], w1[40];
#pragma unroll
    for (int i = 0; i < 39; ++i) {
        w0[i] = W[i * DIMv + c0];
        w1[i] = W[i * DIMv + c1];
    }
    w0[39] = 0.f; w1[39] = 0.f;
    const float be0 = be[c0], be1 = be[c1];
    const float g0 = gain[c0], g1 = gain[c1];
    const float bb0 = bias[c0], bb1 = bias[c1];

    for (int e = 0; e < Kv; ++e) {
        const float* fr = &fls[w][e * 40];
        float a0 = be0, a1 = be1;
#pragma unroll
        for (int q = 0; q < 10; ++q) {
            float4 v = *(const float4*)(fr + 4 * q);   // broadcast ds_read_b128
            a0 = fmaf(v.x, w0[4 * q + 0], a0);
            a1 = fmaf(v.x, w1[4 * q + 0], a1);
            a0 = fmaf(v.y, w0[4 * q + 1], a0);
            a1 = fmaf(v.y, w1[4 * q + 1], a1);
            a0 = fmaf(v.z, w0[4 * q + 2], a0);
            a1 = fmaf(v.z, w1[4 * q + 2], a1);
            a0 = fmaf(v.w, w0[4 * q + 3], a0);
            a1 = fmaf(v.w, w1[4 * q + 3], a1);
        }

        // fused LayerNorm in-wave (sum, sumsq butterflies)
        float s_ = a0 + a1;
        float q_ = fmaf(a0, a0, a1 * a1);
#pragma unroll
        for (int m = 1; m < 64; m <<= 1) {
            s_ += __shfl_xor(s_, m, 64);
            q_ += __shfl_xor(q_, m, 64);
        }
        float mu = s_ * (1.0f / 128.0f);
        float var = fmaxf((q_ - s_ * mu) * (1.0f / 127.0f), 0.f);
        float inv = 1.0f / (sqrtf(var) + 1e-6f);
        float* out = E + (size_t)(rk + e) * DIMv;
        out[c0] = g0 * (a0 - mu) * inv + bb0;
        out[c1] = g1 * (a1 - mu) * inv + bb1;
    }
}

// ---------------- launcher ----------------
extern "C" void kernel_launch(void* const* d_in, const int* in_sizes, int n_in,
                              void* d_out, int out_size, void* d_ws, size_t ws_size,
                              hipStream_t stream) {
    const float* X = (const float*)d_in[0];
    const float* mask = (const float*)d_in[1];
    const float* W_e = (const float*)d_in[2];
    const float* b_e = (const float*)d_in[3];
    const float* gain = (const float*)d_in[4];
    const float* bias = (const float*)d_in[5];

    float* E = (float*)d_out;
    float* idxf = (float*)d_out + (size_t)NEDGE * DIMv;

    char* ws = (char*)d_ws;
    const size_t off_idx = (size_t)NROW * 9 * 4;
    const size_t off_dn = off_idx + (size_t)NEDGE * 4;
    const size_t off_feat = off_dn + (size_t)NEDGE * 4;
    float* O9 = (float*)ws;
    int* idx_ws = (int*)(ws + off_idx);
    float* dn_ws = (float*)(ws + off_dn);
    float* feat = (float*)(ws + off_feat);   // [NEDGE][40] row-major

    hipLaunchKernelGGL(o_kernel, dim3((NROW + 255) / 256), dim3(256), 0, stream, X, O9);
    hipLaunchKernelGGL(topk_kernel, dim3(NROW / 8), dim3(256), 0, stream,
                       X, mask, idx_ws, dn_ws, idxf);
    hipLaunchKernelGGL(feat_kernel, dim3(NEDGE / 256), dim3(256), 0, stream,
                       X, O9, idx_ws, dn_ws, feat);
    hipLaunchKernelGGL(gemm_ln7_kernel, dim3(NROW / 4), dim3(256), 0, stream,
                       W_e, b_e, gain, bias, feat, E);
}